// Round 8
// baseline (316.891 us; speedup 1.0000x reference)
//
#include <hip/hip_runtime.h>
#include <math.h>

#define LAM_INIT 0.2f
#define ONE_MINUS_LAM 0.8f
#define SCALING_F 0.05103103630798288f  // 384^-0.5

typedef _Float16 h2 __attribute__((ext_vector_type(2)));

#if defined(__has_builtin)
#if __has_builtin(__builtin_amdgcn_fdot2)
#define FDOT2(a, b, c) __builtin_amdgcn_fdot2((a), (b), (c), false)
#endif
#endif
#ifndef FDOT2
#define FDOT2(a, b, c) ((float)(a).x * (float)(b).x + ((float)(a).y * (float)(b).y + (c)))
#endif

__device__ inline float waveMin(float v) {
#pragma unroll
    for (int o = 32; o > 0; o >>= 1) v = fminf(v, __shfl_xor(v, o));
    return v;
}
__device__ inline float waveSum(float v) {
#pragma unroll
    for (int o = 32; o > 0; o >>= 1) v += __shfl_xor(v, o);
    return v;
}

// ---------------------------------------------------------------------------
// K01: fused prep. 1285 blocks. (unchanged)
// ---------------------------------------------------------------------------
__global__ __launch_bounds__(256) void k01_prep(
    const float* __restrict__ key, const float* __restrict__ Wq,
    const float* __restrict__ Wkv, const float* __restrict__ Wout,
    const float* __restrict__ lq1, const float* __restrict__ lk1,
    const float* __restrict__ lq2, const float* __restrict__ lk2,
    const float* __restrict__ ln,
    unsigned* __restrict__ keyThU, float* __restrict__ Wcp,
    float* __restrict__ Wvp, float* __restrict__ lam,
    float* __restrict__ M)
{
    int blk = blockIdx.x;
    int tid = threadIdx.x;
    if (blk < 128) {
        int b  = blk >> 4;
        int l0 = (blk & 15) << 8;
        __shared__ float tile[256 * 33];
        const float* kp = key + ((size_t)b * 4096 + l0) * 32;
#pragma unroll
        for (int q = 0; q < 32; ++q) {
            int idx = tid + (q << 8);
            int r = idx >> 5, g = idx & 31;
            tile[r * 33 + g] = kp[idx];
        }
        __syncthreads();
#pragma unroll
        for (int gp = 0; gp < 16; ++gp) {
            h2 v;
            v.x = (_Float16)tile[tid * 33 + 2 * gp];
            v.y = (_Float16)tile[tid * 33 + 2 * gp + 1];
            keyThU[((size_t)(b * 16 + gp)) * 4096 + l0 + tid] =
                __builtin_bit_cast(unsigned, v);
        }
    } else if (blk < 512) {
        int bb = blk - 128;
        int kc = bb & 1;
        int ob = bb >> 1;
        int idx = ob * 256 + tid;
        int e  = idx >> 6;
        int hg = idx & 63;
        int h = hg >> 5, g = hg & 31;
        const float4* wqr = (const float4*)(Wq  + (size_t)e * 768 + h * 384 + kc * 192);
        const float4* wkr = (const float4*)(Wkv + (size_t)g * 1536 + h * 384 + kc * 192);
        float s0 = 0.f, s1 = 0.f;
#pragma unroll 4
        for (int d = 0; d < 48; d += 2) {
            float4 a0 = wqr[d],   b0 = wkr[d];
            float4 a1 = wqr[d+1], b1 = wkr[d+1];
            s0 += a0.x*b0.x + a0.y*b0.y + a0.z*b0.z + a0.w*b0.w;
            s1 += a1.x*b1.x + a1.y*b1.y + a1.z*b1.z + a1.w*b1.w;
        }
        Wcp[kc * 49152 + idx] = (s0 + s1) * SCALING_F;
    } else if (blk < 1280) {
        int bb = blk - 512;
        int kc = bb / 96;
        int ob = bb - kc * 96;
        int idx = ob * 256 + tid;
        int g = idx / 768;
        int e = idx - g * 768;
        const float* wvr = Wkv + (size_t)g * 1536 + 768;
        int c0 = kc * 96;
        float s0 = 0.f, s1 = 0.f;
#pragma unroll 4
        for (int c = c0; c < c0 + 96; c += 2) {
            s0 += wvr[c]   * ln[c]   * Wout[(size_t)c * 768 + e];
            s1 += wvr[c+1] * ln[c+1] * Wout[(size_t)(c+1) * 768 + e];
        }
        Wvp[kc * 24576 + idx] = s0 + s1;
    } else if (blk == 1280) {
        float s1 = 0.f, s2 = 0.f;
        for (int d = tid; d < 384; d += 256) {
            s1 += lq1[d] * lk1[d];
            s2 += lq2[d] * lk2[d];
        }
        s1 = waveSum(s1);
        s2 = waveSum(s2);
        __shared__ float r1[4], r2[4];
        int wid = tid >> 6, lane = tid & 63;
        if (lane == 0) { r1[wid] = s1; r2[wid] = s2; }
        __syncthreads();
        if (tid == 0) {
            float a  = r1[0] + r1[1] + r1[2] + r1[3];
            float b2 = r2[0] + r2[1] + r2[2] + r2[3];
            lam[0] = expf(a) - expf(b2) + LAM_INIT;
        }
    } else {
        int idx = (blk - 1281) * 256 + tid;
        int g = idx >> 5, gp = idx & 31;
        const float4* ra = (const float4*)(Wkv + (size_t)g  * 1536 + 768);
        const float4* rb = (const float4*)(Wkv + (size_t)gp * 1536 + 768);
        float s = 0.f;
#pragma unroll 4
        for (int q = 0; q < 192; ++q) {
            float4 a = ra[q], b = rb[q];
            s += a.x*b.x + a.y*b.y + a.z*b.z + a.w*b.w;
        }
        M[idx] = s;
    }
}

// ---------------------------------------------------------------------------
// K2 v4: (unchanged) Qt GEMM split-K x4 + WvoT reduce/transpose tail.
// ---------------------------------------------------------------------------
__global__ __launch_bounds__(256) void k2_qt(
    const float* __restrict__ query, const float* __restrict__ Wcp,
    const float* __restrict__ Wvp, float* __restrict__ WvoT,
    float* __restrict__ Qtp)
{
    int blk = blockIdx.x;
    int tid = threadIdx.x;
    if (blk >= 512) {
        int idx = (blk - 512) * 256 + tid;
        float s = 0.f;
#pragma unroll
        for (int kc = 0; kc < 8; ++kc) s += Wvp[kc * 24576 + idx];
        int g = idx / 768;
        int e = idx - g * 768;
        WvoT[(size_t)e * 32 + g] = s;
        return;
    }
    int kc = blk >> 7;
    int mt = blk & 127;
    int m0 = mt * 32;
    __shared__ __align__(16) float As[64 * 33];
    __shared__ __align__(16) float Bs[64 * 64];

    int tm = tid >> 5;
    int tn = tid & 31;
    float acc[4][2];
#pragma unroll
    for (int r = 0; r < 4; ++r) { acc[r][0] = 0.f; acc[r][1] = 0.f; }

    for (int ch = 0; ch < 3; ++ch) {
        int k0 = kc * 192 + ch * 64;
        __syncthreads();
#pragma unroll
        for (int q = 0; q < 2; ++q) {
            int f = tid + q * 256;
            int m = f >> 4, kq = f & 15;
            float4 v = *(const float4*)&query[(size_t)(m0 + m) * 768 + k0 + kq * 4];
            As[(kq * 4 + 0) * 33 + m] = v.x;
            As[(kq * 4 + 1) * 33 + m] = v.y;
            As[(kq * 4 + 2) * 33 + m] = v.z;
            As[(kq * 4 + 3) * 33 + m] = v.w;
        }
#pragma unroll
        for (int q = 0; q < 4; ++q) {
            int f = tid + q * 256;
            int kk = f >> 4, n4 = f & 15;
            float4 a = *(const float4*)&Wcp[(size_t)(k0 + kk) * 64 + n4 * 4];
            float4 b = *(const float4*)&Wcp[49152 + (size_t)(k0 + kk) * 64 + n4 * 4];
            float4 s; s.x = a.x + b.x; s.y = a.y + b.y; s.z = a.z + b.z; s.w = a.w + b.w;
            *(float4*)&Bs[kk * 64 + n4 * 4] = s;
        }
        __syncthreads();
#pragma unroll 8
        for (int kk = 0; kk < 64; ++kk) {
            float4 a = *(const float4*)&As[kk * 33 + tm * 4];
            float2 b = *(const float2*)&Bs[kk * 64 + tn * 2];
            acc[0][0] += a.x * b.x; acc[0][1] += a.x * b.y;
            acc[1][0] += a.y * b.x; acc[1][1] += a.y * b.y;
            acc[2][0] += a.z * b.x; acc[2][1] += a.z * b.y;
            acc[3][0] += a.w * b.x; acc[3][1] += a.w * b.y;
        }
    }
#pragma unroll
    for (int r = 0; r < 4; ++r) {
        float2 o; o.x = acc[r][0]; o.y = acc[r][1];
        *(float2*)&Qtp[(size_t)kc * 262144 + (size_t)(m0 + tm * 4 + r) * 64 + tn * 2] = o;
    }
}

// ---------------------------------------------------------------------------
// K3 v7: (unchanged) 1024 blocks x 512 threads, 4 s-rows/block, no max-pass.
// ---------------------------------------------------------------------------
__global__ __launch_bounds__(512, 4) void k3_attn(
    const float* __restrict__ Qtp, const unsigned* __restrict__ keyThU,
    const int* __restrict__ qmask, const int* __restrict__ kmask,
    const float* __restrict__ lamp, float* __restrict__ diffO)
{
    int blk = blockIdx.x;
    int b  = blk >> 7;
    int s0 = (blk & 127) * 4;
    int tid = threadIdx.x;
    int lane = tid & 63, wid = tid >> 6;

    __shared__ __align__(16) unsigned qt_th[128];
    __shared__ float redS[64];
    __shared__ float redM[32];

    if (tid < 128) {
        int ts = tid >> 5;
        int h  = (tid >> 4) & 1;
        int gp = tid & 15;
        size_t row = (size_t)(b * 512 + s0 + ts) * 64;
        int col = h * 32 + 2 * gp;
        float v0 = 0.f, v1 = 0.f;
#pragma unroll
        for (int kc = 0; kc < 4; ++kc) {
            v0 += Qtp[(size_t)kc * 262144 + row + col];
            v1 += Qtp[(size_t)kc * 262144 + row + col + 1];
        }
        h2 hv; hv.x = (_Float16)v0; hv.y = (_Float16)v1;
        qt_th[gp * 8 + ts * 2 + h] = __builtin_bit_cast(unsigned, hv);
    }
    int qm[4];
#pragma unroll
    for (int ts = 0; ts < 4; ++ts) qm[ts] = qmask[b * 512 + s0 + ts];
    float lam = lamp[0];

    unsigned kmb = 0;
#pragma unroll
    for (int c = 0; c < 2; ++c) {
        int4 km = *(const int4*)(kmask + b * 4096 + c * 2048 + tid * 4);
        if (km.x) kmb |= 1u << (c * 4 + 0);
        if (km.y) kmb |= 1u << (c * 4 + 1);
        if (km.z) kmb |= 1u << (c * 4 + 2);
        if (km.w) kmb |= 1u << (c * 4 + 3);
    }
    __syncthreads();

    float p[2][4][8];
#pragma unroll
    for (int h = 0; h < 2; ++h)
#pragma unroll
        for (int ts = 0; ts < 4; ++ts)
#pragma unroll
            for (int i = 0; i < 8; ++i) p[h][ts][i] = 0.f;

    const unsigned* kt = keyThU + (size_t)b * 16 * 4096 + tid * 4;
    for (int gp = 0; gp < 16; ++gp) {
        uint4 q0 = *(const uint4*)&qt_th[gp * 8];
        uint4 q1 = *(const uint4*)&qt_th[gp * 8 + 4];
        h2 qv[8];
        qv[0] = __builtin_bit_cast(h2, q0.x); qv[1] = __builtin_bit_cast(h2, q0.y);
        qv[2] = __builtin_bit_cast(h2, q0.z); qv[3] = __builtin_bit_cast(h2, q0.w);
        qv[4] = __builtin_bit_cast(h2, q1.x); qv[5] = __builtin_bit_cast(h2, q1.y);
        qv[6] = __builtin_bit_cast(h2, q1.z); qv[7] = __builtin_bit_cast(h2, q1.w);
        const unsigned* kg = kt + (size_t)gp * 4096;
#pragma unroll
        for (int c = 0; c < 2; ++c) {
            uint4 kv = *(const uint4*)(kg + c * 2048);
            h2 k0 = __builtin_bit_cast(h2, kv.x);
            h2 k1 = __builtin_bit_cast(h2, kv.y);
            h2 k2 = __builtin_bit_cast(h2, kv.z);
            h2 k3 = __builtin_bit_cast(h2, kv.w);
#pragma unroll
            for (int ts = 0; ts < 4; ++ts)
#pragma unroll
                for (int h = 0; h < 2; ++h) {
                    h2 q = qv[ts * 2 + h];
                    p[h][ts][c*4+0] = FDOT2(k0, q, p[h][ts][c*4+0]);
                    p[h][ts][c*4+1] = FDOT2(k1, q, p[h][ts][c*4+1]);
                    p[h][ts][c*4+2] = FDOT2(k2, q, p[h][ts][c*4+2]);
                    p[h][ts][c*4+3] = FDOT2(k3, q, p[h][ts][c*4+3]);
                }
        }
    }

    float inv[2][4];
#pragma unroll
    for (int h = 0; h < 2; ++h)
#pragma unroll
        for (int ts = 0; ts < 4; ++ts) {
            float s = 0.f;
#pragma unroll
            for (int i = 0; i < 8; ++i) {
                bool ok = qm[ts] && ((kmb >> i) & 1u);
                float e = ok ? __expf(p[h][ts][i]) : 0.f;
                p[h][ts][i] = e;
                s += e;
            }
            s = waveSum(s);
            if (lane == 0) redS[(h * 4 + ts) * 8 + wid] = s;
        }
    __syncthreads();
#pragma unroll
    for (int h = 0; h < 2; ++h)
#pragma unroll
        for (int ts = 0; ts < 4; ++ts) {
            int r = (h * 4 + ts) * 8;
            float s = redS[r];
#pragma unroll
            for (int w = 1; w < 8; ++w) s += redS[r + w];
            inv[h][ts] = 1.0f / (s + 1e-8f);
        }

    float mn[4];
#pragma unroll
    for (int ts = 0; ts < 4; ++ts) {
        float v = 3.4e38f;
#pragma unroll
        for (int i = 0; i < 8; ++i) {
            float d = p[0][ts][i] * inv[0][ts] - lam * (p[1][ts][i] * inv[1][ts]);
            p[0][ts][i] = d;
            v = fminf(v, d);
        }
        v = waveMin(v);
        if (lane == 0) redM[ts * 8 + wid] = v;
    }
    __syncthreads();
#pragma unroll
    for (int ts = 0; ts < 4; ++ts) {
        int r = ts * 8;
        float v = redM[r];
#pragma unroll
        for (int w = 1; w < 8; ++w) v = fminf(v, redM[r + w]);
        mn[ts] = v;
    }

#pragma unroll
    for (int ts = 0; ts < 4; ++ts) {
        size_t base = (size_t)(b * 512 + s0 + ts) * 4096 + tid * 4;
#pragma unroll
        for (int c = 0; c < 2; ++c) {
            float4 o;
            float v0 = p[0][ts][c*4+0] - mn[ts] + 1e-20f;
            float v1 = p[0][ts][c*4+1] - mn[ts] + 1e-20f;
            float v2 = p[0][ts][c*4+2] - mn[ts] + 1e-20f;
            float v3 = p[0][ts][c*4+3] - mn[ts] + 1e-20f;
            o.x = (qm[ts] && ((kmb >> (c*4+0)) & 1u)) ? v0 : 0.f;
            o.y = (qm[ts] && ((kmb >> (c*4+1)) & 1u)) ? v1 : 0.f;
            o.z = (qm[ts] && ((kmb >> (c*4+2)) & 1u)) ? v2 : 0.f;
            o.w = (qm[ts] && ((kmb >> (c*4+3)) & 1u)) ? v3 : 0.f;
            *(float4*)(diffO + base + c * 2048) = o;
        }
    }
}

// ---------------------------------------------------------------------------
// K4_OUT v4: HBM-pipeline fix. 512 blocks x 256 threads, 8 rows/block.
// Diagnosis (r7): diff stream ran at 630 GB/s because only ~100 B/thread of
// HBM reads were in flight (Little's law). Fix: reg-staged double-buffered
// chunk pipeline (T14): chunk ch+1's 8KB of diff loads issue right after
// ch's LDS write and ride in flight under ch's compute (~4 MB chip-wide).
// Static reg names rA0/rA1 (no runtime buffer index -> no scratch, rule #20).
// LDS diff buffer padded to 260 f/row: compute ds_read_b128 hits 4 distinct
// bank-quads (2-way aliasing = free, m136). key read direct from L2 (v3's
// good idea). Epilogue: proven Gram ssq + WvoT GEMM, wave per 2 rows.
// ---------------------------------------------------------------------------
__global__ __launch_bounds__(256) void k4_out(
    const float* __restrict__ diff, const float* __restrict__ key,
    const float* __restrict__ M, const float* __restrict__ WvoT,
    float* __restrict__ out)
{
    int row0 = blockIdx.x * 8;   // 0..4088
    int b = row0 >> 9;
    int tid = threadIdx.x;
    int lq = tid >> 5;           // 0..7 : 32-l slice within a 256-l chunk
    int rp = (tid >> 3) & 3;     // 0..3 : row pair
    int gq = tid & 7;            // 0..7 : g quad
    int g0 = gq * 4;

    __shared__ __align__(16) float db[2][8 * 260];  // 2 x 8.125 KB (padded)
    __shared__ __align__(16) float Tp[8][8][32];    // 8 KB partials
    __shared__ __align__(16) float Ml[1024];        // 4 KB Gram
    __shared__ __align__(16) float Ts[8][32];       // 1 KB

#pragma unroll
    for (int q = 0; q < 4; ++q) Ml[tid + q * 256] = M[tid + q * 256];

    // staging geometry: thread covers f4 #tid and #tid+256 of the 512-f4 chunk
    int r8 = tid >> 6;           // 0..3 (second f4 is row r8+4)
    int c4 = tid & 63;           // f4 column (l = c4*4)
    const float* dg0 = diff + (size_t)(row0 + r8)     * 4096 + c4 * 4;
    const float* dg1 = diff + (size_t)(row0 + r8 + 4) * 4096 + c4 * 4;
    const float* kb  = key + (size_t)b * 4096 * 32;

    float acc[2][4];
#pragma unroll
    for (int r = 0; r < 2; ++r)
#pragma unroll
        for (int c = 0; c < 4; ++c) acc[r][c] = 0.f;

    // prologue: chunk 0 into regs
    float4 rA0 = *(const float4*)(dg0);
    float4 rA1 = *(const float4*)(dg1);

    for (int ch = 0; ch < 16; ++ch) {
        float* dbuf = db[ch & 1];
        __syncthreads();                       // buffer free (compute ch-2 done)
        *(float4*)&dbuf[r8 * 260 + c4 * 4]       = rA0;
        *(float4*)&dbuf[(r8 + 4) * 260 + c4 * 4] = rA1;
        if (ch < 15) {                         // issue next chunk NOW (T14)
            rA0 = *(const float4*)(dg0 + (ch + 1) * 256);
            rA1 = *(const float4*)(dg1 + (ch + 1) * 256);
        }
        __syncthreads();                       // data ready

        const float* kc  = kb + (size_t)(ch * 256 + lq * 32) * 32 + g0;
        const float* dl0 = &dbuf[(rp * 2 + 0) * 260 + lq * 32];
        const float* dl1 = &dbuf[(rp * 2 + 1) * 260 + lq * 32];
#pragma unroll
        for (int j4 = 0; j4 < 8; ++j4) {
            float4 dv0 = *(const float4*)(dl0 + j4 * 4);
            float4 dv1 = *(const float4*)(dl1 + j4 * 4);
#pragma unroll
            for (int c = 0; c < 4; ++c) {
                float4 kq = *(const float4*)(kc + (size_t)(j4 * 4 + c) * 32);
                float a  = (c == 0) ? dv0.x : (c == 1) ? dv0.y : (c == 2) ? dv0.z : dv0.w;
                float bq = (c == 0) ? dv1.x : (c == 1) ? dv1.y : (c == 2) ? dv1.z : dv1.w;
                acc[0][0] += a * kq.x;  acc[0][1] += a * kq.y;
                acc[0][2] += a * kq.z;  acc[0][3] += a * kq.w;
                acc[1][0] += bq * kq.x; acc[1][1] += bq * kq.y;
                acc[1][2] += bq * kq.z; acc[1][3] += bq * kq.w;
            }
        }
    }

    // write l-slice partials
    {
        float4 o0; o0.x = acc[0][0]; o0.y = acc[0][1]; o0.z = acc[0][2]; o0.w = acc[0][3];
        float4 o1; o1.x = acc[1][0]; o1.y = acc[1][1]; o1.z = acc[1][2]; o1.w = acc[1][3];
        *(float4*)&Tp[lq][rp * 2 + 0][g0] = o0;
        *(float4*)&Tp[lq][rp * 2 + 1][g0] = o1;
    }
    __syncthreads();

    // reduce 8 l-slices -> Ts[8][32]
    {
        int r = tid >> 5, g = tid & 31;
        float s = 0.f;
#pragma unroll
        for (int q = 0; q < 8; ++q) s += Tp[q][r][g];
        Ts[r][g] = s;
    }
    __syncthreads();

    // epilogue: wave w owns rows 2w, 2w+1
    int w = tid >> 6, l6 = tid & 63;
#pragma unroll
    for (int rr = 0; rr < 2; ++rr) {
        int r = 2 * w + rr;
        float ssqp = 0.f;
#pragma unroll
        for (int k = 0; k < 16; ++k) {
            int gg = l6 + k * 64;
            ssqp = fmaf(Ts[r][gg >> 5] * Ts[r][gg & 31], Ml[gg], ssqp);
        }
        ssqp = waveSum(ssqp);
        float rs = rsqrtf(ssqp * (1.0f / 768.0f) + 1e-5f) * ONE_MINUS_LAM;

        float4 t[8];
#pragma unroll
        for (int q = 0; q < 8; ++q) t[q] = *(const float4*)&Ts[r][q * 4];
#pragma unroll
        for (int j = 0; j < 3; ++j) {
            int e0 = l6 * 4 + j * 256;
            const float4* wp = (const float4*)(WvoT + (size_t)e0 * 32);
            float4 o; o.x = 0.f; o.y = 0.f; o.z = 0.f; o.w = 0.f;
#pragma unroll
            for (int q = 0; q < 8; ++q) {
                float4 a0 = wp[q];        // row e0
                float4 a1 = wp[q + 8];    // row e0+1
                float4 a2 = wp[q + 16];   // row e0+2
                float4 a3 = wp[q + 24];   // row e0+3
                o.x += t[q].x*a0.x + t[q].y*a0.y + t[q].z*a0.z + t[q].w*a0.w;
                o.y += t[q].x*a1.x + t[q].y*a1.y + t[q].z*a1.z + t[q].w*a1.w;
                o.z += t[q].x*a2.x + t[q].y*a2.y + t[q].z*a2.z + t[q].w*a2.w;
                o.w += t[q].x*a3.x + t[q].y*a3.y + t[q].z*a3.z + t[q].w*a3.w;
            }
            o.x *= rs; o.y *= rs; o.z *= rs; o.w *= rs;
            *(float4*)(out + (size_t)(row0 + r) * 768 + e0) = o;
        }
    }
}

// ---------------------------------------------------------------------------
extern "C" void kernel_launch(void* const* d_in, const int* in_sizes, int n_in,
                              void* d_out, int out_size, void* d_ws, size_t ws_size,
                              hipStream_t stream) {
    (void)in_sizes; (void)n_in; (void)out_size; (void)ws_size;
    const float* query = (const float*)d_in[0];
    const float* key   = (const float*)d_in[1];
    const int*   qmask = (const int*)d_in[2];
    const int*   kmask = (const int*)d_in[3];
    const float* Wq    = (const float*)d_in[4];
    const float* Wkv   = (const float*)d_in[5];
    const float* Wout  = (const float*)d_in[6];
    const float* lq1   = (const float*)d_in[7];
    const float* lk1   = (const float*)d_in[8];
    const float* lq2   = (const float*)d_in[9];
    const float* lk2   = (const float*)d_in[10];
    const float* ln    = (const float*)d_in[11];

    float* out  = (float*)d_out;          // (B,S,E) = 3,145,728 floats
    float* diff = out + 3145728;          // (B,S,L) = 16,777,216 floats

    float* ws      = (float*)d_ws;
    float* Wcp     = ws;                    // 98304  (2 Wcomb partials)
    float* WvoT    = ws + 98304;            // 24576  (transposed [e][g])
    float* Wvp     = ws + 122880;           // 196608 (8 Wvo partials)
    float* lam     = ws + 319488;           // 64
    unsigned* keyThU = (unsigned*)(ws + 319552); // 524288 u32 (half2-packed keyT)
    float* Qtp     = ws + 843840;           // 1048576 (4 Qt partials)
    float* Mbuf    = ws + 1892416;          // 1024 (Gram matrix Wv@Wv^T)
                                            // total ~7.57 MB

    k01_prep<<<1285, 256, 0, stream>>>(key, Wq, Wkv, Wout, lq1, lk1, lq2, lk2, ln,
                                       keyThU, Wcp, Wvp, lam, Mbuf);
    k2_qt<<<608, 256, 0, stream>>>(query, Wcp, Wvp, WvoT, Qtp);
    k3_attn<<<1024, 512, 0, stream>>>(Qtp, keyThU, qmask, kmask, lam, diff);
    k4_out<<<512, 256, 0, stream>>>(diff, key, Mbuf, WvoT, out);
}

// Round 9
// 250.216 us; speedup vs baseline: 1.2665x; 1.2665x over previous
//
#include <hip/hip_runtime.h>
#include <math.h>

#define LAM_INIT 0.2f
#define ONE_MINUS_LAM 0.8f
#define SCALING_F 0.05103103630798288f  // 384^-0.5

typedef _Float16 h2 __attribute__((ext_vector_type(2)));

#if defined(__has_builtin)
#if __has_builtin(__builtin_amdgcn_fdot2)
#define FDOT2(a, b, c) __builtin_amdgcn_fdot2((a), (b), (c), false)
#endif
#endif
#ifndef FDOT2
#define FDOT2(a, b, c) ((float)(a).x * (float)(b).x + ((float)(a).y * (float)(b).y + (c)))
#endif

__device__ inline float waveMin(float v) {
#pragma unroll
    for (int o = 32; o > 0; o >>= 1) v = fminf(v, __shfl_xor(v, o));
    return v;
}
__device__ inline float waveSum(float v) {
#pragma unroll
    for (int o = 32; o > 0; o >>= 1) v += __shfl_xor(v, o);
    return v;
}

// ---------------------------------------------------------------------------
// K01: fused prep. 1281 blocks:
//  [0,128):   transpose key (B,L,32) -> keyTh packed half2 [b][gpair][l]
//  [128,512): Wcomb split-K x2 -> Wcp[kc] partials (direct store, no atomics)
//  [512,1280): Wvo split-K x8 -> Wvp[kc] partials (direct store)
//  [1280]:    lam scalar
// ---------------------------------------------------------------------------
__global__ __launch_bounds__(256) void k01_prep(
    const float* __restrict__ key, const float* __restrict__ Wq,
    const float* __restrict__ Wkv, const float* __restrict__ Wout,
    const float* __restrict__ lq1, const float* __restrict__ lk1,
    const float* __restrict__ lq2, const float* __restrict__ lk2,
    const float* __restrict__ ln,
    unsigned* __restrict__ keyThU, float* __restrict__ Wcp,
    float* __restrict__ Wvp, float* __restrict__ lam)
{
    int blk = blockIdx.x;
    int tid = threadIdx.x;
    if (blk < 128) {
        // --- transpose + fp16 pack ---
        int b  = blk >> 4;
        int l0 = (blk & 15) << 8;
        __shared__ float tile[256 * 33];
        const float* kp = key + ((size_t)b * 4096 + l0) * 32;
#pragma unroll
        for (int q = 0; q < 32; ++q) {
            int idx = tid + (q << 8);
            int r = idx >> 5, g = idx & 31;
            tile[r * 33 + g] = kp[idx];
        }
        __syncthreads();
#pragma unroll
        for (int gp = 0; gp < 16; ++gp) {
            h2 v;
            v.x = (_Float16)tile[tid * 33 + 2 * gp];
            v.y = (_Float16)tile[tid * 33 + 2 * gp + 1];
            keyThU[((size_t)(b * 16 + gp)) * 4096 + l0 + tid] =
                __builtin_bit_cast(unsigned, v);
        }
    } else if (blk < 512) {
        // --- Wcomb partials, split-K x2 ---
        int bb = blk - 128;
        int kc = bb & 1;
        int ob = bb >> 1;            // 0..191
        int idx = ob * 256 + tid;    // 0..49151
        int e  = idx >> 6;
        int hg = idx & 63;
        int h = hg >> 5, g = hg & 31;
        const float4* wqr = (const float4*)(Wq  + (size_t)e * 768 + h * 384 + kc * 192);
        const float4* wkr = (const float4*)(Wkv + (size_t)g * 1536 + h * 384 + kc * 192);
        float s0 = 0.f, s1 = 0.f;
#pragma unroll 4
        for (int d = 0; d < 48; d += 2) {
            float4 a0 = wqr[d],   b0 = wkr[d];
            float4 a1 = wqr[d+1], b1 = wkr[d+1];
            s0 += a0.x*b0.x + a0.y*b0.y + a0.z*b0.z + a0.w*b0.w;
            s1 += a1.x*b1.x + a1.y*b1.y + a1.z*b1.z + a1.w*b1.w;
        }
        Wcp[kc * 49152 + idx] = (s0 + s1) * SCALING_F;
    } else if (blk < 1280) {
        // --- Wvo partials, split-K x8 ---
        int bb = blk - 512;
        int kc = bb / 96;
        int ob = bb - kc * 96;
        int idx = ob * 256 + tid;    // 0..24575
        int g = idx / 768;
        int e = idx - g * 768;
        const float* wvr = Wkv + (size_t)g * 1536 + 768;
        int c0 = kc * 96;
        float s0 = 0.f, s1 = 0.f;
#pragma unroll 4
        for (int c = c0; c < c0 + 96; c += 2) {
            s0 += wvr[c]   * ln[c]   * Wout[(size_t)c * 768 + e];
            s1 += wvr[c+1] * ln[c+1] * Wout[(size_t)(c+1) * 768 + e];
        }
        Wvp[kc * 24576 + idx] = s0 + s1;
    } else {
        float s1 = 0.f, s2 = 0.f;
        for (int d = tid; d < 384; d += 256) {
            s1 += lq1[d] * lk1[d];
            s2 += lq2[d] * lk2[d];
        }
        s1 = waveSum(s1);
        s2 = waveSum(s2);
        __shared__ float r1[4], r2[4];
        int wid = tid >> 6, lane = tid & 63;
        if (lane == 0) { r1[wid] = s1; r2[wid] = s2; }
        __syncthreads();
        if (tid == 0) {
            float a  = r1[0] + r1[1] + r1[2] + r1[3];
            float b2 = r2[0] + r2[1] + r2[2] + r2[3];
            lam[0] = expf(a) - expf(b2) + LAM_INIT;
        }
    }
}

// ---------------------------------------------------------------------------
// K2 v3: tiled GEMM Qt = query @ Wcomb with split-K x4 -> Qtp partials.
// Blocks [0,512): kc = blk>>7, mt = blk&127 (32 m-rows). BK=64 chunks (3).
// As stored k-major [64][33] (padded), Bs[64][64] = Wcp0+Wcp1 summed on stage.
// Thread: tm=tid>>5 (4 m-rows), tn=tid&31 (2 n-cols) -> acc[4][2].
// Blocks [512,608): Wvo = sum of 8 Wvp partials.
// ---------------------------------------------------------------------------
__global__ __launch_bounds__(256) void k2_qt(
    const float* __restrict__ query, const float* __restrict__ Wcp,
    const float* __restrict__ Wvp, float* __restrict__ Wvo,
    float* __restrict__ Qtp)
{
    int blk = blockIdx.x;
    int tid = threadIdx.x;
    if (blk >= 512) {
        int idx = (blk - 512) * 256 + tid;   // 0..24575
        float s = 0.f;
#pragma unroll
        for (int kc = 0; kc < 8; ++kc) s += Wvp[kc * 24576 + idx];
        Wvo[idx] = s;
        return;
    }
    int kc = blk >> 7;          // 0..3
    int mt = blk & 127;
    int m0 = mt * 32;
    __shared__ __align__(16) float As[64 * 33];
    __shared__ __align__(16) float Bs[64 * 64];

    int tm = tid >> 5;          // 0..7 -> rows tm*4..+3
    int tn = tid & 31;          // cols tn*2, tn*2+1
    float acc[4][2];
#pragma unroll
    for (int r = 0; r < 4; ++r) { acc[r][0] = 0.f; acc[r][1] = 0.f; }

    for (int ch = 0; ch < 3; ++ch) {
        int k0 = kc * 192 + ch * 64;
        __syncthreads();
        // stage As (k-major, padded 33)
#pragma unroll
        for (int q = 0; q < 2; ++q) {
            int f = tid + q * 256;          // 0..511 float4s
            int m = f >> 4, kq = f & 15;
            float4 v = *(const float4*)&query[(size_t)(m0 + m) * 768 + k0 + kq * 4];
            As[(kq * 4 + 0) * 33 + m] = v.x;
            As[(kq * 4 + 1) * 33 + m] = v.y;
            As[(kq * 4 + 2) * 33 + m] = v.z;
            As[(kq * 4 + 3) * 33 + m] = v.w;
        }
        // stage Bs = Wcp0 + Wcp1
#pragma unroll
        for (int q = 0; q < 4; ++q) {
            int f = tid + q * 256;          // 0..1023 float4s
            int kk = f >> 4, n4 = f & 15;
            float4 a = *(const float4*)&Wcp[(size_t)(k0 + kk) * 64 + n4 * 4];
            float4 b = *(const float4*)&Wcp[49152 + (size_t)(k0 + kk) * 64 + n4 * 4];
            float4 s; s.x = a.x + b.x; s.y = a.y + b.y; s.z = a.z + b.z; s.w = a.w + b.w;
            *(float4*)&Bs[kk * 64 + n4 * 4] = s;
        }
        __syncthreads();
#pragma unroll 8
        for (int kk = 0; kk < 64; ++kk) {
            float4 a = *(const float4*)&As[kk * 33 + tm * 4];
            float2 b = *(const float2*)&Bs[kk * 64 + tn * 2];
            acc[0][0] += a.x * b.x; acc[0][1] += a.x * b.y;
            acc[1][0] += a.y * b.x; acc[1][1] += a.y * b.y;
            acc[2][0] += a.z * b.x; acc[2][1] += a.z * b.y;
            acc[3][0] += a.w * b.x; acc[3][1] += a.w * b.y;
        }
    }
#pragma unroll
    for (int r = 0; r < 4; ++r) {
        float2 o; o.x = acc[r][0]; o.y = acc[r][1];
        *(float2*)&Qtp[(size_t)kc * 262144 + (size_t)(m0 + tm * 4 + r) * 64 + tn * 2] = o;
    }
}

// ---------------------------------------------------------------------------
// K3 v7: 1024 blocks x 512 threads, 4 s-rows/block, no max-subtraction pass
// (scores tiny -> exp(s) exact fp32; softmax shift-invariant; HW-validated).
// ---------------------------------------------------------------------------
__global__ __launch_bounds__(512, 4) void k3_attn(
    const float* __restrict__ Qtp, const unsigned* __restrict__ keyThU,
    const int* __restrict__ qmask, const int* __restrict__ kmask,
    const float* __restrict__ lamp, float* __restrict__ diffO)
{
    int blk = blockIdx.x;
    int b  = blk >> 7;
    int s0 = (blk & 127) * 4;
    int tid = threadIdx.x;
    int lane = tid & 63, wid = tid >> 6;   // 8 waves

    __shared__ __align__(16) unsigned qt_th[128];  // [gp*8 + ts*2 + h]
    __shared__ float redS[64];
    __shared__ float redM[32];

    if (tid < 128) {
        int ts = tid >> 5;
        int h  = (tid >> 4) & 1;
        int gp = tid & 15;
        size_t row = (size_t)(b * 512 + s0 + ts) * 64;
        int col = h * 32 + 2 * gp;
        float v0 = 0.f, v1 = 0.f;
#pragma unroll
        for (int kc = 0; kc < 4; ++kc) {
            v0 += Qtp[(size_t)kc * 262144 + row + col];
            v1 += Qtp[(size_t)kc * 262144 + row + col + 1];
        }
        h2 hv; hv.x = (_Float16)v0; hv.y = (_Float16)v1;
        qt_th[gp * 8 + ts * 2 + h] = __builtin_bit_cast(unsigned, hv);
    }
    int qm[4];
#pragma unroll
    for (int ts = 0; ts < 4; ++ts) qm[ts] = qmask[b * 512 + s0 + ts];
    float lam = lamp[0];

    unsigned kmb = 0;
#pragma unroll
    for (int c = 0; c < 2; ++c) {
        int4 km = *(const int4*)(kmask + b * 4096 + c * 2048 + tid * 4);
        if (km.x) kmb |= 1u << (c * 4 + 0);
        if (km.y) kmb |= 1u << (c * 4 + 1);
        if (km.z) kmb |= 1u << (c * 4 + 2);
        if (km.w) kmb |= 1u << (c * 4 + 3);
    }
    __syncthreads();

    float p[2][4][8];
#pragma unroll
    for (int h = 0; h < 2; ++h)
#pragma unroll
        for (int ts = 0; ts < 4; ++ts)
#pragma unroll
            for (int i = 0; i < 8; ++i) p[h][ts][i] = 0.f;

    const unsigned* kt = keyThU + (size_t)b * 16 * 4096 + tid * 4;
    for (int gp = 0; gp < 16; ++gp) {
        uint4 q0 = *(const uint4*)&qt_th[gp * 8];
        uint4 q1 = *(const uint4*)&qt_th[gp * 8 + 4];
        h2 qv[8];
        qv[0] = __builtin_bit_cast(h2, q0.x); qv[1] = __builtin_bit_cast(h2, q0.y);
        qv[2] = __builtin_bit_cast(h2, q0.z); qv[3] = __builtin_bit_cast(h2, q0.w);
        qv[4] = __builtin_bit_cast(h2, q1.x); qv[5] = __builtin_bit_cast(h2, q1.y);
        qv[6] = __builtin_bit_cast(h2, q1.z); qv[7] = __builtin_bit_cast(h2, q1.w);
        const unsigned* kg = kt + (size_t)gp * 4096;
#pragma unroll
        for (int c = 0; c < 2; ++c) {
            uint4 kv = *(const uint4*)(kg + c * 2048);
            h2 k0 = __builtin_bit_cast(h2, kv.x);
            h2 k1 = __builtin_bit_cast(h2, kv.y);
            h2 k2 = __builtin_bit_cast(h2, kv.z);
            h2 k3 = __builtin_bit_cast(h2, kv.w);
#pragma unroll
            for (int ts = 0; ts < 4; ++ts)
#pragma unroll
                for (int h = 0; h < 2; ++h) {
                    h2 q = qv[ts * 2 + h];
                    p[h][ts][c*4+0] = FDOT2(k0, q, p[h][ts][c*4+0]);
                    p[h][ts][c*4+1] = FDOT2(k1, q, p[h][ts][c*4+1]);
                    p[h][ts][c*4+2] = FDOT2(k2, q, p[h][ts][c*4+2]);
                    p[h][ts][c*4+3] = FDOT2(k3, q, p[h][ts][c*4+3]);
                }
        }
    }

    // fused mask + exp (no max-subtraction) + row-sum
    float inv[2][4];
#pragma unroll
    for (int h = 0; h < 2; ++h)
#pragma unroll
        for (int ts = 0; ts < 4; ++ts) {
            float s = 0.f;
#pragma unroll
            for (int i = 0; i < 8; ++i) {
                bool ok = qm[ts] && ((kmb >> i) & 1u);
                float e = ok ? __expf(p[h][ts][i]) : 0.f;
                p[h][ts][i] = e;
                s += e;
            }
            s = waveSum(s);
            if (lane == 0) redS[(h * 4 + ts) * 8 + wid] = s;
        }
    __syncthreads();
#pragma unroll
    for (int h = 0; h < 2; ++h)
#pragma unroll
        for (int ts = 0; ts < 4; ++ts) {
            int r = (h * 4 + ts) * 8;
            float s = redS[r];
#pragma unroll
            for (int w = 1; w < 8; ++w) s += redS[r + w];
            inv[h][ts] = 1.0f / (s + 1e-8f);
        }

    float mn[4];
#pragma unroll
    for (int ts = 0; ts < 4; ++ts) {
        float v = 3.4e38f;
#pragma unroll
        for (int i = 0; i < 8; ++i) {
            float d = p[0][ts][i] * inv[0][ts] - lam * (p[1][ts][i] * inv[1][ts]);
            p[0][ts][i] = d;
            v = fminf(v, d);
        }
        v = waveMin(v);
        if (lane == 0) redM[ts * 8 + wid] = v;
    }
    __syncthreads();
#pragma unroll
    for (int ts = 0; ts < 4; ++ts) {
        int r = ts * 8;
        float v = redM[r];
#pragma unroll
        for (int w = 1; w < 8; ++w) v = fminf(v, redM[r + w]);
        mn[ts] = v;
    }

#pragma unroll
    for (int ts = 0; ts < 4; ++ts) {
        size_t base = (size_t)(b * 512 + s0 + ts) * 4096 + tid * 4;
#pragma unroll
        for (int c = 0; c < 2; ++c) {
            float4 o;
            float v0 = p[0][ts][c*4+0] - mn[ts] + 1e-20f;
            float v1 = p[0][ts][c*4+1] - mn[ts] + 1e-20f;
            float v2 = p[0][ts][c*4+2] - mn[ts] + 1e-20f;
            float v3 = p[0][ts][c*4+3] - mn[ts] + 1e-20f;
            o.x = (qm[ts] && ((kmb >> (c*4+0)) & 1u)) ? v0 : 0.f;
            o.y = (qm[ts] && ((kmb >> (c*4+1)) & 1u)) ? v1 : 0.f;
            o.z = (qm[ts] && ((kmb >> (c*4+2)) & 1u)) ? v2 : 0.f;
            o.w = (qm[ts] && ((kmb >> (c*4+3)) & 1u)) ? v3 : 0.f;
            *(float4*)(diffO + base + c * 2048) = o;
        }
    }
}

// ---------------------------------------------------------------------------
// K4 v3: T partials. 512 blocks = 64 row-tiles(64) x 8 k-chunks(512 l).
// Thread (tx=g-quad, ty -> 2 rows). Two 256-l LDS phases. Direct stores to P.
// ---------------------------------------------------------------------------
__global__ __launch_bounds__(256) void k4_T(
    const float* __restrict__ diff, const float* __restrict__ key,
    float* __restrict__ P)
{
    int blk = blockIdx.x;
    int rt = blk & 63, kc = blk >> 6;   // rt<64, kc<8
    int row0 = rt << 6;     // *64
    int b = row0 >> 9;
    int l0 = kc << 9;       // *512
    int tid = threadIdx.x;
    int tx = tid & 7;       // g0 = tx*4
    int ty = tid >> 3;      // rows row0 + ty*2 + r
    int g0 = tx * 4;

    __shared__ __align__(16) float Ks[256][32];

    float acc[2][4];
#pragma unroll
    for (int r = 0; r < 2; ++r)
#pragma unroll
        for (int c2 = 0; c2 < 4; ++c2) acc[r][c2] = 0.f;

    for (int ph = 0; ph < 2; ++ph) {
        int lp = l0 + ph * 256;
        __syncthreads();
#pragma unroll
        for (int q = 0; q < 32; ++q) {
            int idx = tid + (q << 8);
            int r = idx >> 5, g = idx & 31;
            Ks[r][g] = key[((size_t)(b * 4096 + lp + r)) * 32 + g];
        }
        __syncthreads();

        for (int j4 = 0; j4 < 64; ++j4) {
            int l = lp + j4 * 4;
            float4 dv[2];
#pragma unroll
            for (int r = 0; r < 2; ++r)
                dv[r] = *(const float4*)(diff + (size_t)(row0 + ty * 2 + r) * 4096 + l);
#pragma unroll
            for (int jj = 0; jj < 4; ++jj) {
                float4 kq = *(const float4*)&Ks[j4 * 4 + jj][g0];
#pragma unroll
                for (int r = 0; r < 2; ++r) {
                    float d = (jj == 0) ? dv[r].x : (jj == 1) ? dv[r].y : (jj == 2) ? dv[r].z : dv[r].w;
                    acc[r][0] += d * kq.x;
                    acc[r][1] += d * kq.y;
                    acc[r][2] += d * kq.z;
                    acc[r][3] += d * kq.w;
                }
            }
        }
    }
#pragma unroll
    for (int r = 0; r < 2; ++r) {
        float4 o; o.x = acc[r][0]; o.y = acc[r][1]; o.z = acc[r][2]; o.w = acc[r][3];
        *(float4*)&P[(size_t)kc * 131072 + (size_t)(row0 + ty * 2 + r) * 32 + g0] = o;
    }
}

// ---------------------------------------------------------------------------
// K5 v2: row-per-wave, no cross-wave coupling. 1024 blocks x 256 threads,
// 4 rows/block (1 per wave). T row held in 32 VGPRs; each lane owns 12 cols.
// ssq via in-wave shfl reduce only; zero barriers after the initial stage.
// Best measured final-stage variant (52.6 us, round 3).
// ---------------------------------------------------------------------------
__global__ __launch_bounds__(256, 4) void k5_out(
    const float* __restrict__ P, const float* __restrict__ Wkv,
    const float* __restrict__ Wvo, float* __restrict__ out)
{
    int row0 = blockIdx.x * 4;
    int tid = threadIdx.x;
    int w = tid >> 6;        // wave id = local row index
    int lane = tid & 63;
    __shared__ __align__(16) float Ts[4][32];

    if (tid < 128) {
        int r = tid >> 5, g = tid & 31;
        float s = 0.f;
#pragma unroll
        for (int kc = 0; kc < 8; ++kc)
            s += P[(size_t)kc * 131072 + (size_t)(row0 + r) * 32 + g];
        Ts[r][g] = s;
    }
    __syncthreads();

    // pull my row into registers (broadcast b128 reads, conflict-free)
    float4 t[8];
#pragma unroll
    for (int q = 0; q < 8; ++q) t[q] = *(const float4*)&Ts[w][q * 4];

    // phase A: ssq = sum_e (T . Wv[:,e])^2 over this lane's 12 cols
    float ssq = 0.f;
#pragma unroll 2
    for (int j = 0; j < 12; ++j) {
        int e = lane + j * 64;
        const float* wp = Wkv + 768 + e;
        float a = 0.f;
#pragma unroll
        for (int q = 0; q < 8; ++q) {
            a += t[q].x * wp[(size_t)(q * 4 + 0) * 1536];
            a += t[q].y * wp[(size_t)(q * 4 + 1) * 1536];
            a += t[q].z * wp[(size_t)(q * 4 + 2) * 1536];
            a += t[q].w * wp[(size_t)(q * 4 + 3) * 1536];
        }
        ssq += a * a;
    }
    ssq = waveSum(ssq);
    float rs = rsqrtf(ssq * (1.0f / 768.0f) + 1e-5f) * ONE_MINUS_LAM;

    // phase B: out row = rs * (T @ Wvo)
#pragma unroll 2
    for (int j = 0; j < 12; ++j) {
        int e = lane + j * 64;
        const float* wp = Wvo + e;
        float o = 0.f;
#pragma unroll
        for (int q = 0; q < 8; ++q) {
            o += t[q].x * wp[(size_t)(q * 4 + 0) * 768];
            o += t[q].y * wp[(size_t)(q * 4 + 1) * 768];
            o += t[q].z * wp[(size_t)(q * 4 + 2) * 768];
            o += t[q].w * wp[(size_t)(q * 4 + 3) * 768];
        }
        out[(size_t)(row0 + w) * 768 + e] = o * rs;
    }
}

// ---------------------------------------------------------------------------
extern "C" void kernel_launch(void* const* d_in, const int* in_sizes, int n_in,
                              void* d_out, int out_size, void* d_ws, size_t ws_size,
                              hipStream_t stream) {
    (void)in_sizes; (void)n_in; (void)out_size; (void)ws_size;
    const float* query = (const float*)d_in[0];
    const float* key   = (const float*)d_in[1];
    const int*   qmask = (const int*)d_in[2];
    const int*   kmask = (const int*)d_in[3];
    const float* Wq    = (const float*)d_in[4];
    const float* Wkv   = (const float*)d_in[5];
    const float* Wout  = (const float*)d_in[6];
    const float* lq1   = (const float*)d_in[7];
    const float* lk1   = (const float*)d_in[8];
    const float* lq2   = (const float*)d_in[9];
    const float* lk2   = (const float*)d_in[10];
    const float* ln    = (const float*)d_in[11];

    float* out  = (float*)d_out;          // (B,S,E) = 3,145,728 floats
    float* diff = out + 3145728;          // (B,S,L) = 16,777,216 floats

    float* ws      = (float*)d_ws;
    float* Wcp     = ws;                    // 98304  (2 Wcomb partials)
    float* Wvo     = ws + 98304;            // 24576
    float* Wvp     = ws + 122880;           // 196608 (8 Wvo partials)
    float* lam     = ws + 319488;           // 64
    unsigned* keyThU = (unsigned*)(ws + 319552); // 524288 u32 (half2-packed keyT)
    float* Qtp     = ws + 843840;           // 1048576 (4 Qt partials)
    float* P       = Qtp;                   // alias: Qtp dead after k3; P written by k4
                                            // total ~7.6 MB

    k01_prep<<<1281, 256, 0, stream>>>(key, Wq, Wkv, Wout, lq1, lk1, lq2, lk2, ln,
                                       keyThU, Wcp, Wvp, lam);
    k2_qt<<<608, 256, 0, stream>>>(query, Wcp, Wvp, Wvo, Qtp);
    k3_attn<<<1024, 512, 0, stream>>>(Qtp, keyThU, qmask, kmask, lam, diff);
    k4_T<<<512, 256, 0, stream>>>(diff, key, P);
    k5_out<<<1024, 256, 0, stream>>>(P, Wkv, Wvo, out);
}

// Round 10
// 234.152 us; speedup vs baseline: 1.3534x; 1.0686x over previous
//
#include <hip/hip_runtime.h>
#include <math.h>

#define LAM_INIT 0.2f
#define ONE_MINUS_LAM 0.8f
#define SCALING_F 0.05103103630798288f  // 384^-0.5

typedef _Float16 h2 __attribute__((ext_vector_type(2)));

#if defined(__has_builtin)
#if __has_builtin(__builtin_amdgcn_fdot2)
#define FDOT2(a, b, c) __builtin_amdgcn_fdot2((a), (b), (c), false)
#endif
#endif
#ifndef FDOT2
#define FDOT2(a, b, c) ((float)(a).x * (float)(b).x + ((float)(a).y * (float)(b).y + (c)))
#endif

__device__ inline float waveMin(float v) {
#pragma unroll
    for (int o = 32; o > 0; o >>= 1) v = fminf(v, __shfl_xor(v, o));
    return v;
}
__device__ inline float waveSum(float v) {
#pragma unroll
    for (int o = 32; o > 0; o >>= 1) v += __shfl_xor(v, o);
    return v;
}

// ---------------------------------------------------------------------------
// K01: fused prep. 1285 blocks:
//  [0,128):    transpose key (B,L,32) -> keyTh packed half2 [b][gpair][l]
//  [128,512):  Wcomb split-K x2 -> Wcp[kc] partials
//  [512,1280): Wvo split-K x8 -> Wvp[kc] partials
//  [1280]:     lam scalar
//  [1281,1285): M = Wv @ Wv^T (32x32 Gram for k5 rms statistic)
// ---------------------------------------------------------------------------
__global__ __launch_bounds__(256) void k01_prep(
    const float* __restrict__ key, const float* __restrict__ Wq,
    const float* __restrict__ Wkv, const float* __restrict__ Wout,
    const float* __restrict__ lq1, const float* __restrict__ lk1,
    const float* __restrict__ lq2, const float* __restrict__ lk2,
    const float* __restrict__ ln,
    unsigned* __restrict__ keyThU, float* __restrict__ Wcp,
    float* __restrict__ Wvp, float* __restrict__ lam,
    float* __restrict__ M)
{
    int blk = blockIdx.x;
    int tid = threadIdx.x;
    if (blk < 128) {
        // --- transpose + fp16 pack ---
        int b  = blk >> 4;
        int l0 = (blk & 15) << 8;
        __shared__ float tile[256 * 33];
        const float* kp = key + ((size_t)b * 4096 + l0) * 32;
#pragma unroll
        for (int q = 0; q < 32; ++q) {
            int idx = tid + (q << 8);
            int r = idx >> 5, g = idx & 31;
            tile[r * 33 + g] = kp[idx];
        }
        __syncthreads();
#pragma unroll
        for (int gp = 0; gp < 16; ++gp) {
            h2 v;
            v.x = (_Float16)tile[tid * 33 + 2 * gp];
            v.y = (_Float16)tile[tid * 33 + 2 * gp + 1];
            keyThU[((size_t)(b * 16 + gp)) * 4096 + l0 + tid] =
                __builtin_bit_cast(unsigned, v);
        }
    } else if (blk < 512) {
        // --- Wcomb partials, split-K x2 ---
        int bb = blk - 128;
        int kc = bb & 1;
        int ob = bb >> 1;            // 0..191
        int idx = ob * 256 + tid;    // 0..49151
        int e  = idx >> 6;
        int hg = idx & 63;
        int h = hg >> 5, g = hg & 31;
        const float4* wqr = (const float4*)(Wq  + (size_t)e * 768 + h * 384 + kc * 192);
        const float4* wkr = (const float4*)(Wkv + (size_t)g * 1536 + h * 384 + kc * 192);
        float s0 = 0.f, s1 = 0.f;
#pragma unroll 4
        for (int d = 0; d < 48; d += 2) {
            float4 a0 = wqr[d],   b0 = wkr[d];
            float4 a1 = wqr[d+1], b1 = wkr[d+1];
            s0 += a0.x*b0.x + a0.y*b0.y + a0.z*b0.z + a0.w*b0.w;
            s1 += a1.x*b1.x + a1.y*b1.y + a1.z*b1.z + a1.w*b1.w;
        }
        Wcp[kc * 49152 + idx] = (s0 + s1) * SCALING_F;
    } else if (blk < 1280) {
        // --- Wvo partials, split-K x8 ---
        int bb = blk - 512;
        int kc = bb / 96;
        int ob = bb - kc * 96;
        int idx = ob * 256 + tid;    // 0..24575
        int g = idx / 768;
        int e = idx - g * 768;
        const float* wvr = Wkv + (size_t)g * 1536 + 768;
        int c0 = kc * 96;
        float s0 = 0.f, s1 = 0.f;
#pragma unroll 4
        for (int c = c0; c < c0 + 96; c += 2) {
            s0 += wvr[c]   * ln[c]   * Wout[(size_t)c * 768 + e];
            s1 += wvr[c+1] * ln[c+1] * Wout[(size_t)(c+1) * 768 + e];
        }
        Wvp[kc * 24576 + idx] = s0 + s1;
    } else if (blk == 1280) {
        float s1 = 0.f, s2 = 0.f;
        for (int d = tid; d < 384; d += 256) {
            s1 += lq1[d] * lk1[d];
            s2 += lq2[d] * lk2[d];
        }
        s1 = waveSum(s1);
        s2 = waveSum(s2);
        __shared__ float r1[4], r2[4];
        int wid = tid >> 6, lane = tid & 63;
        if (lane == 0) { r1[wid] = s1; r2[wid] = s2; }
        __syncthreads();
        if (tid == 0) {
            float a  = r1[0] + r1[1] + r1[2] + r1[3];
            float b2 = r2[0] + r2[1] + r2[2] + r2[3];
            lam[0] = expf(a) - expf(b2) + LAM_INIT;
        }
    } else {
        // --- M = Wv @ Wv^T, 1024 entries over 4 blocks ---
        int idx = (blk - 1281) * 256 + tid;  // 0..1023
        int g = idx >> 5, gp = idx & 31;
        const float4* ra = (const float4*)(Wkv + (size_t)g  * 1536 + 768);
        const float4* rb = (const float4*)(Wkv + (size_t)gp * 1536 + 768);
        float s = 0.f;
#pragma unroll 4
        for (int q = 0; q < 192; ++q) {
            float4 a = ra[q], b = rb[q];
            s += a.x*b.x + a.y*b.y + a.z*b.z + a.w*b.w;
        }
        M[idx] = s;
    }
}

// ---------------------------------------------------------------------------
// K2 v3: (unchanged) Qt GEMM split-K x4 + plain Wvo reduce tail.
// ---------------------------------------------------------------------------
__global__ __launch_bounds__(256) void k2_qt(
    const float* __restrict__ query, const float* __restrict__ Wcp,
    const float* __restrict__ Wvp, float* __restrict__ Wvo,
    float* __restrict__ Qtp)
{
    int blk = blockIdx.x;
    int tid = threadIdx.x;
    if (blk >= 512) {
        int idx = (blk - 512) * 256 + tid;   // 0..24575
        float s = 0.f;
#pragma unroll
        for (int kc = 0; kc < 8; ++kc) s += Wvp[kc * 24576 + idx];
        Wvo[idx] = s;
        return;
    }
    int kc = blk >> 7;          // 0..3
    int mt = blk & 127;
    int m0 = mt * 32;
    __shared__ __align__(16) float As[64 * 33];
    __shared__ __align__(16) float Bs[64 * 64];

    int tm = tid >> 5;          // 0..7 -> rows tm*4..+3
    int tn = tid & 31;          // cols tn*2, tn*2+1
    float acc[4][2];
#pragma unroll
    for (int r = 0; r < 4; ++r) { acc[r][0] = 0.f; acc[r][1] = 0.f; }

    for (int ch = 0; ch < 3; ++ch) {
        int k0 = kc * 192 + ch * 64;
        __syncthreads();
        // stage As (k-major, padded 33)
#pragma unroll
        for (int q = 0; q < 2; ++q) {
            int f = tid + q * 256;          // 0..511 float4s
            int m = f >> 4, kq = f & 15;
            float4 v = *(const float4*)&query[(size_t)(m0 + m) * 768 + k0 + kq * 4];
            As[(kq * 4 + 0) * 33 + m] = v.x;
            As[(kq * 4 + 1) * 33 + m] = v.y;
            As[(kq * 4 + 2) * 33 + m] = v.z;
            As[(kq * 4 + 3) * 33 + m] = v.w;
        }
        // stage Bs = Wcp0 + Wcp1
#pragma unroll
        for (int q = 0; q < 4; ++q) {
            int f = tid + q * 256;          // 0..1023 float4s
            int kk = f >> 4, n4 = f & 15;
            float4 a = *(const float4*)&Wcp[(size_t)(k0 + kk) * 64 + n4 * 4];
            float4 b = *(const float4*)&Wcp[49152 + (size_t)(k0 + kk) * 64 + n4 * 4];
            float4 s; s.x = a.x + b.x; s.y = a.y + b.y; s.z = a.z + b.z; s.w = a.w + b.w;
            *(float4*)&Bs[kk * 64 + n4 * 4] = s;
        }
        __syncthreads();
#pragma unroll 8
        for (int kk = 0; kk < 64; ++kk) {
            float4 a = *(const float4*)&As[kk * 33 + tm * 4];
            float2 b = *(const float2*)&Bs[kk * 64 + tn * 2];
            acc[0][0] += a.x * b.x; acc[0][1] += a.x * b.y;
            acc[1][0] += a.y * b.x; acc[1][1] += a.y * b.y;
            acc[2][0] += a.z * b.x; acc[2][1] += a.z * b.y;
            acc[3][0] += a.w * b.x; acc[3][1] += a.w * b.y;
        }
    }
#pragma unroll
    for (int r = 0; r < 4; ++r) {
        float2 o; o.x = acc[r][0]; o.y = acc[r][1];
        *(float2*)&Qtp[(size_t)kc * 262144 + (size_t)(m0 + tm * 4 + r) * 64 + tn * 2] = o;
    }
}

// ---------------------------------------------------------------------------
// K3 v7: (unchanged) 1024 blocks x 512 threads, 4 s-rows/block, no max-pass.
// ---------------------------------------------------------------------------
__global__ __launch_bounds__(512, 4) void k3_attn(
    const float* __restrict__ Qtp, const unsigned* __restrict__ keyThU,
    const int* __restrict__ qmask, const int* __restrict__ kmask,
    const float* __restrict__ lamp, float* __restrict__ diffO)
{
    int blk = blockIdx.x;
    int b  = blk >> 7;
    int s0 = (blk & 127) * 4;
    int tid = threadIdx.x;
    int lane = tid & 63, wid = tid >> 6;   // 8 waves

    __shared__ __align__(16) unsigned qt_th[128];  // [gp*8 + ts*2 + h]
    __shared__ float redS[64];
    __shared__ float redM[32];

    if (tid < 128) {
        int ts = tid >> 5;
        int h  = (tid >> 4) & 1;
        int gp = tid & 15;
        size_t row = (size_t)(b * 512 + s0 + ts) * 64;
        int col = h * 32 + 2 * gp;
        float v0 = 0.f, v1 = 0.f;
#pragma unroll
        for (int kc = 0; kc < 4; ++kc) {
            v0 += Qtp[(size_t)kc * 262144 + row + col];
            v1 += Qtp[(size_t)kc * 262144 + row + col + 1];
        }
        h2 hv; hv.x = (_Float16)v0; hv.y = (_Float16)v1;
        qt_th[gp * 8 + ts * 2 + h] = __builtin_bit_cast(unsigned, hv);
    }
    int qm[4];
#pragma unroll
    for (int ts = 0; ts < 4; ++ts) qm[ts] = qmask[b * 512 + s0 + ts];
    float lam = lamp[0];

    unsigned kmb = 0;
#pragma unroll
    for (int c = 0; c < 2; ++c) {
        int4 km = *(const int4*)(kmask + b * 4096 + c * 2048 + tid * 4);
        if (km.x) kmb |= 1u << (c * 4 + 0);
        if (km.y) kmb |= 1u << (c * 4 + 1);
        if (km.z) kmb |= 1u << (c * 4 + 2);
        if (km.w) kmb |= 1u << (c * 4 + 3);
    }
    __syncthreads();

    float p[2][4][8];
#pragma unroll
    for (int h = 0; h < 2; ++h)
#pragma unroll
        for (int ts = 0; ts < 4; ++ts)
#pragma unroll
            for (int i = 0; i < 8; ++i) p[h][ts][i] = 0.f;

    const unsigned* kt = keyThU + (size_t)b * 16 * 4096 + tid * 4;
    for (int gp = 0; gp < 16; ++gp) {
        uint4 q0 = *(const uint4*)&qt_th[gp * 8];
        uint4 q1 = *(const uint4*)&qt_th[gp * 8 + 4];
        h2 qv[8];
        qv[0] = __builtin_bit_cast(h2, q0.x); qv[1] = __builtin_bit_cast(h2, q0.y);
        qv[2] = __builtin_bit_cast(h2, q0.z); qv[3] = __builtin_bit_cast(h2, q0.w);
        qv[4] = __builtin_bit_cast(h2, q1.x); qv[5] = __builtin_bit_cast(h2, q1.y);
        qv[6] = __builtin_bit_cast(h2, q1.z); qv[7] = __builtin_bit_cast(h2, q1.w);
        const unsigned* kg = kt + (size_t)gp * 4096;
#pragma unroll
        for (int c = 0; c < 2; ++c) {
            uint4 kv = *(const uint4*)(kg + c * 2048);
            h2 k0 = __builtin_bit_cast(h2, kv.x);
            h2 k1 = __builtin_bit_cast(h2, kv.y);
            h2 k2 = __builtin_bit_cast(h2, kv.z);
            h2 k3 = __builtin_bit_cast(h2, kv.w);
#pragma unroll
            for (int ts = 0; ts < 4; ++ts)
#pragma unroll
                for (int h = 0; h < 2; ++h) {
                    h2 q = qv[ts * 2 + h];
                    p[h][ts][c*4+0] = FDOT2(k0, q, p[h][ts][c*4+0]);
                    p[h][ts][c*4+1] = FDOT2(k1, q, p[h][ts][c*4+1]);
                    p[h][ts][c*4+2] = FDOT2(k2, q, p[h][ts][c*4+2]);
                    p[h][ts][c*4+3] = FDOT2(k3, q, p[h][ts][c*4+3]);
                }
        }
    }

    // fused mask + exp (no max-subtraction) + row-sum
    float inv[2][4];
#pragma unroll
    for (int h = 0; h < 2; ++h)
#pragma unroll
        for (int ts = 0; ts < 4; ++ts) {
            float s = 0.f;
#pragma unroll
            for (int i = 0; i < 8; ++i) {
                bool ok = qm[ts] && ((kmb >> i) & 1u);
                float e = ok ? __expf(p[h][ts][i]) : 0.f;
                p[h][ts][i] = e;
                s += e;
            }
            s = waveSum(s);
            if (lane == 0) redS[(h * 4 + ts) * 8 + wid] = s;
        }
    __syncthreads();
#pragma unroll
    for (int h = 0; h < 2; ++h)
#pragma unroll
        for (int ts = 0; ts < 4; ++ts) {
            int r = (h * 4 + ts) * 8;
            float s = redS[r];
#pragma unroll
            for (int w = 1; w < 8; ++w) s += redS[r + w];
            inv[h][ts] = 1.0f / (s + 1e-8f);
        }

    float mn[4];
#pragma unroll
    for (int ts = 0; ts < 4; ++ts) {
        float v = 3.4e38f;
#pragma unroll
        for (int i = 0; i < 8; ++i) {
            float d = p[0][ts][i] * inv[0][ts] - lam * (p[1][ts][i] * inv[1][ts]);
            p[0][ts][i] = d;
            v = fminf(v, d);
        }
        v = waveMin(v);
        if (lane == 0) redM[ts * 8 + wid] = v;
    }
    __syncthreads();
#pragma unroll
    for (int ts = 0; ts < 4; ++ts) {
        int r = ts * 8;
        float v = redM[r];
#pragma unroll
        for (int w = 1; w < 8; ++w) v = fminf(v, redM[r + w]);
        mn[ts] = v;
    }

#pragma unroll
    for (int ts = 0; ts < 4; ++ts) {
        size_t base = (size_t)(b * 512 + s0 + ts) * 4096 + tid * 4;
#pragma unroll
        for (int c = 0; c < 2; ++c) {
            float4 o;
            float v0 = p[0][ts][c*4+0] - mn[ts] + 1e-20f;
            float v1 = p[0][ts][c*4+1] - mn[ts] + 1e-20f;
            float v2 = p[0][ts][c*4+2] - mn[ts] + 1e-20f;
            float v3 = p[0][ts][c*4+3] - mn[ts] + 1e-20f;
            o.x = (qm[ts] && ((kmb >> (c*4+0)) & 1u)) ? v0 : 0.f;
            o.y = (qm[ts] && ((kmb >> (c*4+1)) & 1u)) ? v1 : 0.f;
            o.z = (qm[ts] && ((kmb >> (c*4+2)) & 1u)) ? v2 : 0.f;
            o.w = (qm[ts] && ((kmb >> (c*4+3)) & 1u)) ? v3 : 0.f;
            *(float4*)(diffO + base + c * 2048) = o;
        }
    }
}

// ---------------------------------------------------------------------------
// K4 v3: (unchanged) T partials. 512 blocks = 64 row-tiles x 8 k-chunks.
// ---------------------------------------------------------------------------
__global__ __launch_bounds__(256) void k4_T(
    const float* __restrict__ diff, const float* __restrict__ key,
    float* __restrict__ P)
{
    int blk = blockIdx.x;
    int rt = blk & 63, kc = blk >> 6;   // rt<64, kc<8
    int row0 = rt << 6;     // *64
    int b = row0 >> 9;
    int l0 = kc << 9;       // *512
    int tid = threadIdx.x;
    int tx = tid & 7;       // g0 = tx*4
    int ty = tid >> 3;      // rows row0 + ty*2 + r
    int g0 = tx * 4;

    __shared__ __align__(16) float Ks[256][32];

    float acc[2][4];
#pragma unroll
    for (int r = 0; r < 2; ++r)
#pragma unroll
        for (int c2 = 0; c2 < 4; ++c2) acc[r][c2] = 0.f;

    for (int ph = 0; ph < 2; ++ph) {
        int lp = l0 + ph * 256;
        __syncthreads();
#pragma unroll
        for (int q = 0; q < 32; ++q) {
            int idx = tid + (q << 8);
            int r = idx >> 5, g = idx & 31;
            Ks[r][g] = key[((size_t)(b * 4096 + lp + r)) * 32 + g];
        }
        __syncthreads();

        for (int j4 = 0; j4 < 64; ++j4) {
            int l = lp + j4 * 4;
            float4 dv[2];
#pragma unroll
            for (int r = 0; r < 2; ++r)
                dv[r] = *(const float4*)(diff + (size_t)(row0 + ty * 2 + r) * 4096 + l);
#pragma unroll
            for (int jj = 0; jj < 4; ++jj) {
                float4 kq = *(const float4*)&Ks[j4 * 4 + jj][g0];
#pragma unroll
                for (int r = 0; r < 2; ++r) {
                    float d = (jj == 0) ? dv[r].x : (jj == 1) ? dv[r].y : (jj == 2) ? dv[r].z : dv[r].w;
                    acc[r][0] += d * kq.x;
                    acc[r][1] += d * kq.y;
                    acc[r][2] += d * kq.z;
                    acc[r][3] += d * kq.w;
                }
            }
        }
    }
#pragma unroll
    for (int r = 0; r < 2; ++r) {
        float4 o; o.x = acc[r][0]; o.y = acc[r][1]; o.z = acc[r][2]; o.w = acc[r][3];
        *(float4*)&P[(size_t)kc * 131072 + (size_t)(row0 + ty * 2 + r) * 32 + g0] = o;
    }
}

// ---------------------------------------------------------------------------
// K5 v4: L1-miss fix. 1024 blocks x 256 threads, 4 rows (1/wave).
// Theory: v1/v2/v3 all streamed 98KB+ of weights through the 32KB L1 per
// block -> every weight load was an L1 miss at ~38 cyc/line from L2 (the
// invariant ~51-57us across all three interiors). v4 removes the weight
// stream from the compute path entirely:
//  - phase A (ssq) via Gram matrix Ml in LDS (16 FMA/lane, exact reassoc).
//  - phase B tiles Wvo [32][256] through LDS [32][260] (f4-aligned staging,
//    compute reads at 2 lanes/bank = free per m136). 3 tiles, 2 barriers
//    each, 4-wave block. Weight L2 traffic = 96KB/block, coalesced, once.
// LDS 38KB -> 4 blocks/CU (16 waves). Stores coalesced scalar per lane.
// ---------------------------------------------------------------------------
__global__ __launch_bounds__(256, 4) void k5_out(
    const float* __restrict__ P, const float* __restrict__ M,
    const float* __restrict__ Wvo, float* __restrict__ out)
{
    int row0 = blockIdx.x * 4;
    int tid = threadIdx.x;
    int w = tid >> 6;        // wave id = local row index
    int lane = tid & 63;
    __shared__ __align__(16) float Ts[4][32];
    __shared__ __align__(16) float Ml[1024];
    __shared__ __align__(16) float Wl[32][260];

    if (tid < 128) {
        int r = tid >> 5, g = tid & 31;
        float s = 0.f;
#pragma unroll
        for (int kc = 0; kc < 8; ++kc)
            s += P[(size_t)kc * 131072 + (size_t)(row0 + r) * 32 + g];
        Ts[r][g] = s;
    }
#pragma unroll
    for (int q = 0; q < 4; ++q) Ml[tid + q * 256] = M[tid + q * 256];
    __syncthreads();

    // my row into registers (broadcast reads)
    float4 t[8];
#pragma unroll
    for (int q = 0; q < 8; ++q) t[q] = *(const float4*)&Ts[w][q * 4];

    // phase A: ssq via Gram (16 pairs per lane)
    float ssqp = 0.f;
#pragma unroll
    for (int k = 0; k < 16; ++k) {
        int gg = lane + k * 64;
        ssqp = fmaf(Ts[w][gg >> 5] * Ts[w][gg & 31], Ml[gg], ssqp);
    }
    ssqp = waveSum(ssqp);
    float rs = rsqrtf(ssqp * (1.0f / 768.0f) + 1e-5f) * ONE_MINUS_LAM;

    // phase B: 3 e-tiles of 256; Wvo tile staged in LDS once per block
    for (int tle = 0; tle < 3; ++tle) {
        __syncthreads();   // Wl free (previous tile's compute done)
#pragma unroll
        for (int q = 0; q < 8; ++q) {
            int f = tid + q * 256;        // 0..2047 float4s
            int g = f >> 6, e4 = f & 63;
            *(float4*)&Wl[g][e4 * 4] =
                *(const float4*)&Wvo[(size_t)g * 768 + tle * 256 + e4 * 4];
        }
        __syncthreads();
#pragma unroll
        for (int j = 0; j < 4; ++j) {
            int el = lane + j * 64;
            float o = 0.f;
#pragma unroll
            for (int q = 0; q < 8; ++q) {
                o += t[q].x * Wl[q * 4 + 0][el];
                o += t[q].y * Wl[q * 4 + 1][el];
                o += t[q].z * Wl[q * 4 + 2][el];
                o += t[q].w * Wl[q * 4 + 3][el];
            }
            out[(size_t)(row0 + w) * 768 + tle * 256 + el] = o * rs;
        }
    }
}

// ---------------------------------------------------------------------------
extern "C" void kernel_launch(void* const* d_in, const int* in_sizes, int n_in,
                              void* d_out, int out_size, void* d_ws, size_t ws_size,
                              hipStream_t stream) {
    (void)in_sizes; (void)n_in; (void)out_size; (void)ws_size;
    const float* query = (const float*)d_in[0];
    const float* key   = (const float*)d_in[1];
    const int*   qmask = (const int*)d_in[2];
    const int*   kmask = (const int*)d_in[3];
    const float* Wq    = (const float*)d_in[4];
    const float* Wkv   = (const float*)d_in[5];
    const float* Wout  = (const float*)d_in[6];
    const float* lq1   = (const float*)d_in[7];
    const float* lk1   = (const float*)d_in[8];
    const float* lq2   = (const float*)d_in[9];
    const float* lk2   = (const float*)d_in[10];
    const float* ln    = (const float*)d_in[11];

    float* out  = (float*)d_out;          // (B,S,E) = 3,145,728 floats
    float* diff = out + 3145728;          // (B,S,L) = 16,777,216 floats

    float* ws      = (float*)d_ws;
    float* Wcp     = ws;                    // 98304  (2 Wcomb partials)
    float* Wvo     = ws + 98304;            // 24576
    float* Wvp     = ws + 122880;           // 196608 (8 Wvo partials)
    float* lam     = ws + 319488;           // 64
    unsigned* keyThU = (unsigned*)(ws + 319552); // 524288 u32 (half2-packed keyT)
    float* Qtp     = ws + 843840;           // 1048576 (4 Qt partials)
    float* P       = Qtp;                   // alias: Qtp dead after k3; P written by k4
    float* Mbuf    = ws + 1892416;          // 1024 (Gram matrix Wv@Wv^T)
                                            // total ~7.57 MB

    k01_prep<<<1285, 256, 0, stream>>>(key, Wq, Wkv, Wout, lq1, lk1, lq2, lk2, ln,
                                       keyThU, Wcp, Wvp, lam, Mbuf);
    k2_qt<<<608, 256, 0, stream>>>(query, Wcp, Wvp, Wvo, Qtp);
    k3_attn<<<1024, 512, 0, stream>>>(Qtp, keyThU, qmask, kmask, lam, diff);
    k4_T<<<512, 256, 0, stream>>>(diff, key, P);
    k5_out<<<1024, 256, 0, stream>>>(P, Mbuf, Wvo, out);
}